// Round 6
// baseline (288.240 us; speedup 1.0000x reference)
//
#include <hip/hip_runtime.h>
#include <stdint.h>

typedef float f32x4 __attribute__((ext_vector_type(4)));
typedef __bf16 bf16x8 __attribute__((ext_vector_type(8)));
typedef unsigned short u16x8 __attribute__((ext_vector_type(8)));

#define DEV __device__ __forceinline__

DEV unsigned short f2bf(float f) {
  unsigned int u = __float_as_uint(f);
  unsigned int r = (u + 0x7FFFu + ((u >> 16) & 1u)) >> 16;
  return (unsigned short)r;
}
DEV float b2f(unsigned short h) { return __uint_as_float(((unsigned int)h) << 16); }

DEV void gload16(const void* g, void* l) {
  __builtin_amdgcn_global_load_lds((__attribute__((address_space(1))) void*)(g),
                                   (__attribute__((address_space(3))) void*)(l), 16, 0, 0);
}

// ---------------- weights cast only (x-cast is fused into gemm) ----------
__global__ void cast_w4(const float* __restrict__ Wq, const float* __restrict__ Wk,
                        const float* __restrict__ Wv, const float* __restrict__ Wo,
                        unsigned short* __restrict__ wqkv, unsigned short* __restrict__ wo) {
  int i = blockIdx.x * 256 + threadIdx.x;  // 524288 8-elem units
  int sel = i >> 17, j = i & 131071;
  const float* src = (sel == 0) ? Wq : (sel == 1) ? Wk : (sel == 2) ? Wv : Wo;
  unsigned short* dst = (sel < 3) ? (wqkv + (size_t)sel * 1048576) : wo;
  const float4* p = (const float4*)src + (size_t)j * 2;
  float4 a = p[0], b = p[1];
  u16x8 o;
  o[0] = f2bf(a.x); o[1] = f2bf(a.y); o[2] = f2bf(a.z); o[3] = f2bf(a.w);
  o[4] = f2bf(b.x); o[5] = f2bf(b.y); o[6] = f2bf(b.z); o[7] = f2bf(b.w);
  ((u16x8*)dst)[j] = o;
}

// ---------------- bf16 GEMM, B^T layout (out[m,n] = sum_k A[m,k]*W[n,k]) ----
// 128x128 tile, BK=64, multi-block/CU implicit overlap (no XCD swizzle —
// measured r4/r5: swizzle raised FETCH 143->210MB, +3.5% time).
// MODE 0: A is bf16 (gload_lds), plain fp32 store.
// MODE 1: A is fp32 (reg-staged with fused cast -> swizzled ds_write);
//         qkv scatter with elu+1 on Q,K.
template<int MODE>
__global__ __launch_bounds__(256, 2) void gemm_bt(
    const void* __restrict__ Aptr, const unsigned short* __restrict__ Bw,
    void* __restrict__ out0, unsigned short* __restrict__ qp,
    unsigned short* __restrict__ kp, unsigned short* __restrict__ vp,
    int K, int N, int nTn)
{
  __shared__ unsigned short sA[128 * 64];
  __shared__ unsigned short sB[128 * 64];
  int t = threadIdx.x, w = t >> 6, lane = t & 63, fr = lane & 15, fq = lane >> 4;
  int bid = blockIdx.x;
  int bm = bid / nTn, bn = bid % nTn;
  int wm = w >> 1, wn = w & 1;

  f32x4 acc[4][4];
  f32x4 z4 = {0.f, 0.f, 0.f, 0.f};
#pragma unroll
  for (int mi = 0; mi < 4; ++mi)
#pragma unroll
    for (int ni = 0; ni < 4; ++ni) acc[mi][ni] = z4;

  for (int k0 = 0; k0 < K; k0 += 64) {
    if (MODE == 1) {
      const float* A32 = (const float*)Aptr;
      // B via async gload_lds (inverse-swizzled source, linear dest)
#pragma unroll
      for (int i = 0; i < 4; ++i) {
        int p = (i * 4 + w) * 64 + lane;
        int r = p >> 3;
        int c8 = (p & 7) ^ (r & 7);
        gload16(Bw + (size_t)(bn * 128 + r) * K + k0 + c8 * 8, &sB[(i * 4 + w) * 512]);
      }
      // A: fp32 -> reg -> bf16 -> swizzled ds_write_b128 (fused cast)
      float4 av[4][2];
#pragma unroll
      for (int i = 0; i < 4; ++i) {
        int p = (i * 4 + w) * 64 + lane;
        int r = p >> 3, c8 = p & 7;
        const float* s = A32 + (size_t)(bm * 128 + r) * K + k0 + c8 * 8;
        av[i][0] = *(const float4*)s;
        av[i][1] = *(const float4*)(s + 4);
      }
#pragma unroll
      for (int i = 0; i < 4; ++i) {
        int p = (i * 4 + w) * 64 + lane;
        int r = p >> 3, c8 = p & 7;
        u16x8 o;
        o[0] = f2bf(av[i][0].x); o[1] = f2bf(av[i][0].y);
        o[2] = f2bf(av[i][0].z); o[3] = f2bf(av[i][0].w);
        o[4] = f2bf(av[i][1].x); o[5] = f2bf(av[i][1].y);
        o[6] = f2bf(av[i][1].z); o[7] = f2bf(av[i][1].w);
        *(u16x8*)&sA[(r * 8 + (c8 ^ (r & 7))) * 8] = o;
      }
    } else {
      const unsigned short* A16 = (const unsigned short*)Aptr;
#pragma unroll
      for (int i = 0; i < 4; ++i) {
        int p = (i * 4 + w) * 64 + lane;
        int r = p >> 3;
        int c8 = (p & 7) ^ (r & 7);
        gload16(A16 + (size_t)(bm * 128 + r) * K + k0 + c8 * 8, &sA[(i * 4 + w) * 512]);
        gload16(Bw + (size_t)(bn * 128 + r) * K + k0 + c8 * 8, &sB[(i * 4 + w) * 512]);
      }
    }
    __syncthreads();
#pragma unroll
    for (int ks = 0; ks < 2; ++ks) {
      bf16x8 af[4], bg[4];
#pragma unroll
      for (int mi = 0; mi < 4; ++mi) {
        int r = wm * 64 + mi * 16 + fr;
        int c8 = (ks * 4 + fq) ^ (r & 7);
        af[mi] = *(const bf16x8*)&sA[(r * 8 + c8) * 8];
      }
#pragma unroll
      for (int ni = 0; ni < 4; ++ni) {
        int r = wn * 64 + ni * 16 + fr;
        int c8 = (ks * 4 + fq) ^ (r & 7);
        bg[ni] = *(const bf16x8*)&sB[(r * 8 + c8) * 8];
      }
#pragma unroll
      for (int mi = 0; mi < 4; ++mi)
#pragma unroll
        for (int ni = 0; ni < 4; ++ni)
          acc[mi][ni] = __builtin_amdgcn_mfma_f32_16x16x32_bf16(af[mi], bg[ni], acc[mi][ni], 0, 0, 0);
    }
    __syncthreads();
  }

  if (MODE == 0) {
    float* O = (float*)out0;
#pragma unroll
    for (int mi = 0; mi < 4; ++mi)
#pragma unroll
      for (int ni = 0; ni < 4; ++ni)
#pragma unroll
        for (int j = 0; j < 4; ++j) {
          int m = bm * 128 + wm * 64 + mi * 16 + fq * 4 + j;
          int n = bn * 128 + wn * 64 + ni * 16 + fr;
          O[(size_t)m * N + n] = acc[mi][ni][j];
        }
  } else {
    int tsel = (bn * 128) >> 10;  // 0:Q 1:K 2:V (whole block in one tensor)
    unsigned short* base = (tsel == 0) ? qp : ((tsel == 1) ? kp : vp);
#pragma unroll
    for (int mi = 0; mi < 4; ++mi)
#pragma unroll
      for (int ni = 0; ni < 4; ++ni)
#pragma unroll
        for (int j = 0; j < 4; ++j) {
          int m = bm * 128 + wm * 64 + mi * 16 + fq * 4 + j;  // b*4096 + l
          int n = bn * 128 + wn * 64 + ni * 16 + fr;
          int col1 = n & 1023;
          int h = col1 >> 6, d = col1 & 63;
          int b = m >> 12, l = m & 4095;
          float v = acc[mi][ni][j];
          if (tsel < 2) v = (v > 0.f) ? (v + 1.f) : __expf(v);  // elu(v)+1
          base[(((size_t)(b * 16 + h)) * 4096 + l) * 64 + d] = f2bf(v);
        }
  }
}

// ---------------- pass 1: per-chunk state via MFMA ---------------------------
// S_c[e][d] = sum_s v[s][e]*k[s][d]  (stored Sbuf[bh][c][e][d]); z_c[d] = sum_s k[s][d]
__global__ __launch_bounds__(256) void chunk_state(
    const unsigned short* __restrict__ kb, const unsigned short* __restrict__ vb,
    float* __restrict__ Sbuf, float* __restrict__ zbuf)
{
  __shared__ unsigned short kT[64 * 136];
  __shared__ unsigned short vT[64 * 136];
  int t = threadIdx.x, w = t >> 6, lane = t & 63, fr = lane & 15, fq = lane >> 4;
  int bh = blockIdx.x >> 5, c = blockIdx.x & 31;
  size_t base = ((size_t)bh * 4096 + (size_t)c * 128) * 64;

  int s = t >> 1, d0 = (t & 1) * 32;
  const unsigned short* kpp = kb + base + (size_t)s * 64 + d0;
  const unsigned short* vpp = vb + base + (size_t)s * 64 + d0;
#pragma unroll
  for (int i = 0; i < 4; ++i) {
    u16x8 kr = *(const u16x8*)(kpp + i * 8);
    u16x8 vr = *(const u16x8*)(vpp + i * 8);
#pragma unroll
    for (int j = 0; j < 8; ++j) {
      int d = d0 + i * 8 + j;
      kT[d * 136 + s] = kr[j];
      vT[d * 136 + s] = vr[j];
    }
  }
  __syncthreads();

  f32x4 acc[4];
  f32x4 z4 = {0.f, 0.f, 0.f, 0.f};
#pragma unroll
  for (int n = 0; n < 4; ++n) acc[n] = z4;
#pragma unroll
  for (int ks = 0; ks < 4; ++ks) {
    bf16x8 av = *(const bf16x8*)&vT[(w * 16 + fr) * 136 + ks * 32 + fq * 8];
#pragma unroll
    for (int n = 0; n < 4; ++n) {
      bf16x8 bk = *(const bf16x8*)&kT[(n * 16 + fr) * 136 + ks * 32 + fq * 8];
      acc[n] = __builtin_amdgcn_mfma_f32_16x16x32_bf16(av, bk, acc[n], 0, 0, 0);
    }
  }
  size_t ob = ((size_t)bh * 32 + c) * 4096;
#pragma unroll
  for (int n = 0; n < 4; ++n)
#pragma unroll
    for (int j = 0; j < 4; ++j) {
      int e = w * 16 + fq * 4 + j, d = n * 16 + fr;
      Sbuf[ob + (size_t)e * 64 + d] = acc[n][j];
    }
  if (t < 64) {
    float z = 0.f;
#pragma unroll
    for (int i = 0; i < 16; ++i) {
      u16x8 kr = *(const u16x8*)&kT[t * 136 + i * 8];
#pragma unroll
      for (int j = 0; j < 8; ++j) z += b2f(kr[j]);
    }
    zbuf[((size_t)bh * 32 + c) * 64 + t] = z;
  }
}

// ---------------- pass 2: parallel exclusive prefix (S blocks then z blocks) -
__global__ __launch_bounds__(256) void scan_all(
    const float* __restrict__ Sbuf, const float* __restrict__ zbuf,
    unsigned short* __restrict__ Spref, float* __restrict__ zpref)
{
  if (blockIdx.x < 1024) {
    int idx = blockIdx.x * 256 + threadIdx.x;  // 262144 sequences
    int bh = idx >> 12, i = idx & 4095;
    size_t base = (size_t)bh * 32 * 4096 + i;
    float run = 0.f;
#pragma unroll
    for (int c = 0; c < 32; ++c) {
      float v = Sbuf[base + (size_t)c * 4096];
      Spref[base + (size_t)c * 4096] = f2bf(run);
      run += v;
    }
  } else {
    int idx = (blockIdx.x - 1024) * 256 + threadIdx.x;  // 4096 sequences
    size_t base = (size_t)(idx >> 6) * 32 * 64 + (idx & 63);
    float run = 0.f;
#pragma unroll
    for (int c = 0; c < 32; ++c) {
      float v = zbuf[base + c * 64];
      zpref[base + c * 64] = run;
      run += v;
    }
  }
}

// ---------------- pass 3: per-chunk output (round-4 256-thread version) -----
__global__ __launch_bounds__(256, 2) void chunk_out(
    const unsigned short* __restrict__ qb, const unsigned short* __restrict__ kb,
    const unsigned short* __restrict__ vb, const unsigned short* __restrict__ Spref,
    const float* __restrict__ zpref, unsigned short* __restrict__ attn)
{
  __shared__ unsigned short sq[128 * 64];   // q, swizzled (&7)
  __shared__ unsigned short skv[128 * 64];  // k (swz &7), then v^T [64][128] (swz &15)
  __shared__ unsigned short ss[128 * 128];  // masked scores bf16 (swz &15)
  __shared__ unsigned short sS[80 * 64];    // state rows e=0..63, z at 64, zeros 65..79
  int t = threadIdx.x, w = t >> 6, lane = t & 63, fr = lane & 15, fq = lane >> 4;
  int bh = blockIdx.x >> 5, c = blockIdx.x & 31;
  size_t qkbase = ((size_t)bh * 4096 + (size_t)c * 128) * 64;
  size_t sbase = ((size_t)bh * 32 + c) * 4096;

  u16x8 vreg[4];  // v chunk staged to regs early (T14-style)
#pragma unroll
  for (int i = 0; i < 4; ++i)
    vreg[i] = *(const u16x8*)(vb + qkbase + (size_t)(t * 4 + i) * 8);

#pragma unroll
  for (int i = 0; i < 4; ++i) {
    int p = t * 4 + i, r = p >> 3, c8 = p & 7;
    int sw = (r * 8 + (c8 ^ (r & 7))) * 8;
    *(u16x8*)&sq[sw] = *(const u16x8*)(qb + qkbase + (size_t)p * 8);
    *(u16x8*)&skv[sw] = *(const u16x8*)(kb + qkbase + (size_t)p * 8);
  }
#pragma unroll
  for (int i = 0; i < 2; ++i) {
    int p = t * 2 + i, e = p >> 3, c8 = p & 7;
    *(u16x8*)&sS[(e * 8 + (c8 ^ (e & 7))) * 8] = *(const u16x8*)(Spref + sbase + (size_t)p * 8);
  }
  if (t < 64) sS[64 * 64 + t] = f2bf(zpref[((size_t)bh * 32 + c) * 64 + t]);
  {
    unsigned int* zz = (unsigned int*)&sS[65 * 64];
    for (int i = t; i < 480; i += 256) zz[i] = 0u;
  }
  __syncthreads();

  int rowbase = w * 32;
  bf16x8 aq[2][2];
#pragma unroll
  for (int mi = 0; mi < 2; ++mi)
#pragma unroll
    for (int kt = 0; kt < 2; ++kt) {
      int r = rowbase + mi * 16 + fr;
      int c8 = (kt * 4 + fq) ^ (r & 7);
      aq[mi][kt] = *(const bf16x8*)&sq[(r * 8 + c8) * 8];
    }

  f32x4 accs[2][8];
  f32x4 z4 = {0.f, 0.f, 0.f, 0.f};
#pragma unroll
  for (int mi = 0; mi < 2; ++mi)
#pragma unroll
    for (int ni = 0; ni < 8; ++ni) accs[mi][ni] = z4;

#pragma unroll
  for (int ni = 0; ni < 8; ++ni)
#pragma unroll
    for (int kt = 0; kt < 2; ++kt) {
      int r = ni * 16 + fr;
      int c8 = (kt * 4 + fq) ^ (r & 7);
      bf16x8 bk = *(const bf16x8*)&skv[(r * 8 + c8) * 8];
      accs[0][ni] = __builtin_amdgcn_mfma_f32_16x16x32_bf16(aq[0][kt], bk, accs[0][ni], 0, 0, 0);
      accs[1][ni] = __builtin_amdgcn_mfma_f32_16x16x32_bf16(aq[1][kt], bk, accs[1][ni], 0, 0, 0);
    }

  float rs[2][4];
#pragma unroll
  for (int mi = 0; mi < 2; ++mi)
#pragma unroll
    for (int j = 0; j < 4; ++j) {
      int srow = rowbase + mi * 16 + fq * 4 + j;
      float sum = 0.f;
#pragma unroll
      for (int ni = 0; ni < 8; ++ni) {
        int scol = ni * 16 + fr;
        float v = accs[mi][ni][j];
        v = (scol <= srow) ? v : 0.f;
        accs[mi][ni][j] = v;
        sum += v;
      }
#pragma unroll
      for (int msk = 1; msk < 16; msk <<= 1) sum += __shfl_xor(sum, msk, 64);
      rs[mi][j] = sum;
    }
  __syncthreads();  // all waves done reading k from skv

  // write v^T into skv (row e, col s; swizzle &15), masked scores into ss
#pragma unroll
  for (int i = 0; i < 4; ++i) {
    int p = t * 4 + i, s = p >> 3, e0g = (p & 7) * 8;
#pragma unroll
    for (int j = 0; j < 8; ++j) {
      int e = e0g + j;
      skv[(e * 16 + ((s >> 3) ^ (e & 15))) * 8 + (s & 7)] = vreg[i][j];
    }
  }
#pragma unroll
  for (int mi = 0; mi < 2; ++mi)
#pragma unroll
    for (int ni = 0; ni < 8; ++ni)
#pragma unroll
      for (int j = 0; j < 4; ++j) {
        int srow = rowbase + mi * 16 + fq * 4 + j;
        int scol = ni * 16 + fr;
        ss[(srow * 16 + ((scol >> 3) ^ (srow & 15))) * 8 + (scol & 7)] = f2bf(accs[mi][ni][j]);
      }
  __syncthreads();

  f32x4 acco[2][4];
  f32x4 accd[2];
#pragma unroll
  for (int mi = 0; mi < 2; ++mi) {
    accd[mi] = z4;
#pragma unroll
    for (int ni = 0; ni < 4; ++ni) acco[mi][ni] = z4;
  }
  // inter-chunk: q @ S (+ den column from z row)
#pragma unroll
  for (int kt = 0; kt < 2; ++kt) {
#pragma unroll
    for (int ni = 0; ni < 4; ++ni) {
      int r = ni * 16 + fr;
      int c8 = (kt * 4 + fq) ^ (r & 7);
      bf16x8 bS = *(const bf16x8*)&sS[(r * 8 + c8) * 8];
      acco[0][ni] = __builtin_amdgcn_mfma_f32_16x16x32_bf16(aq[0][kt], bS, acco[0][ni], 0, 0, 0);
      acco[1][ni] = __builtin_amdgcn_mfma_f32_16x16x32_bf16(aq[1][kt], bS, acco[1][ni], 0, 0, 0);
    }
    {
      int r = 64 + fr;
      int c8 = (kt * 4 + fq) ^ (r & 7);
      bf16x8 bz = *(const bf16x8*)&sS[(r * 8 + c8) * 8];
      accd[0] = __builtin_amdgcn_mfma_f32_16x16x32_bf16(aq[0][kt], bz, accd[0], 0, 0, 0);
      accd[1] = __builtin_amdgcn_mfma_f32_16x16x32_bf16(aq[1][kt], bz, accd[1], 0, 0, 0);
    }
  }
  // intra-chunk: masked_scores @ v
#pragma unroll
  for (int kt = 0; kt < 4; ++kt) {
    bf16x8 am[2];
#pragma unroll
    for (int mi = 0; mi < 2; ++mi) {
      int r = rowbase + mi * 16 + fr;
      int c8 = (kt * 4 + fq) ^ (r & 15);
      am[mi] = *(const bf16x8*)&ss[(r * 16 + c8) * 8];
    }
#pragma unroll
    for (int ni = 0; ni < 4; ++ni) {
      int r = ni * 16 + fr;
      int c8 = (kt * 4 + fq) ^ (r & 15);
      bf16x8 bv = *(const bf16x8*)&skv[(r * 16 + c8) * 8];
      acco[0][ni] = __builtin_amdgcn_mfma_f32_16x16x32_bf16(am[0], bv, acco[0][ni], 0, 0, 0);
      acco[1][ni] = __builtin_amdgcn_mfma_f32_16x16x32_bf16(am[1], bv, acco[1][ni], 0, 0, 0);
    }
  }

  int b = bh >> 4, h = bh & 15;
#pragma unroll
  for (int mi = 0; mi < 2; ++mi)
#pragma unroll
    for (int j = 0; j < 4; ++j) {
      float den = __shfl(accd[mi][j], (lane & 48), 64) + rs[mi][j];
      float rden = 1.f / den;
      int m = rowbase + mi * 16 + fq * 4 + j;
      size_t rowoff = ((size_t)b * 4096 + (size_t)c * 128 + m) * 1024 + h * 64;
#pragma unroll
      for (int ni = 0; ni < 4; ++ni) {
        int e = ni * 16 + fr;
        float o = acco[mi][ni][j] * rden + 1e-12f;
        attn[rowoff + e] = f2bf(o);
      }
    }
}

// ---------------- host launch ------------------------------------------------
extern "C" void kernel_launch(void* const* d_in, const int* in_sizes, int n_in,
                              void* d_out, int out_size, void* d_ws, size_t ws_size,
                              hipStream_t stream) {
  (void)in_sizes; (void)n_in; (void)out_size; (void)ws_size;
  const float* x = (const float*)d_in[0];
  const float* Wq = (const float*)d_in[1];
  const float* Wk = (const float*)d_in[2];
  const float* Wv = (const float*)d_in[3];
  const float* Wo = (const float*)d_in[4];
  char* ws = (char*)d_ws;
  unsigned short* wqkv = (unsigned short*)(ws + 33554432);   // 6291456 B
  unsigned short* wo   = (unsigned short*)(ws + 39845888);   // 2097152 B
  unsigned short* q    = (unsigned short*)(ws + 41943040);   // 33554432 B
  unsigned short* k    = (unsigned short*)(ws + 75497472);   // 33554432 B
  unsigned short* v    = (unsigned short*)(ws + 109051904);  // 33554432 B
  unsigned short* attn = (unsigned short*)(ws + 142606336);  // 33554432 B
  float* Sbuf          = (float*)(ws + 176160768);           // 33554432 B
  unsigned short* Spref= (unsigned short*)(ws + 209715200);  // 16777216 B
  float* zbuf          = (float*)(ws + 226492416);           // 524288 B
  float* zpref         = (float*)(ws + 227016704);           // 524288 B

  cast_w4<<<2048, 256, 0, stream>>>(Wq, Wk, Wv, Wo, wqkv, wo);
  gemm_bt<1><<<3072, 256, 0, stream>>>(x, wqkv, nullptr, q, k, v, 1024, 3072, 24);
  chunk_state<<<2048, 256, 0, stream>>>(k, v, Sbuf, zbuf);
  scan_all<<<1040, 256, 0, stream>>>(Sbuf, zbuf, Spref, zpref);
  chunk_out<<<2048, 256, 0, stream>>>(q, k, v, Spref, zpref, attn);
  gemm_bt<0><<<1024, 256, 0, stream>>>(attn, wo, d_out, nullptr, nullptr, nullptr, 1024, 1024, 8);
}

// Round 7
// 242.047 us; speedup vs baseline: 1.1908x; 1.1908x over previous
//
#include <hip/hip_runtime.h>
#include <stdint.h>

typedef float f32x4 __attribute__((ext_vector_type(4)));
typedef __bf16 bf16x8 __attribute__((ext_vector_type(8)));
typedef unsigned short u16x8 __attribute__((ext_vector_type(8)));

#define DEV __device__ __forceinline__

DEV unsigned short f2bf(float f) {
  unsigned int u = __float_as_uint(f);
  unsigned int r = (u + 0x7FFFu + ((u >> 16) & 1u)) >> 16;
  return (unsigned short)r;
}
DEV float b2f(unsigned short h) { return __uint_as_float(((unsigned int)h) << 16); }

DEV void gload16(const void* g, void* l) {
  __builtin_amdgcn_global_load_lds((__attribute__((address_space(1))) void*)(g),
                                   (__attribute__((address_space(3))) void*)(l), 16, 0, 0);
}

// ---------------- all casts fused: x (2M units) + 4 weights (512K units) ----
__global__ void cast_all(const float* __restrict__ x, const float* __restrict__ Wq,
                         const float* __restrict__ Wk, const float* __restrict__ Wv,
                         const float* __restrict__ Wo, unsigned short* __restrict__ xbf,
                         unsigned short* __restrict__ wqkv, unsigned short* __restrict__ wo) {
  int i = blockIdx.x * 256 + threadIdx.x;
  const float* src;
  unsigned short* dst;
  int j;
  if (i < 2097152) {
    src = x; dst = xbf; j = i;
  } else {
    int k = i - 2097152;           // 524288 units
    int sel = k >> 17; j = k & 131071;
    src = (sel == 0) ? Wq : (sel == 1) ? Wk : (sel == 2) ? Wv : Wo;
    dst = (sel < 3) ? (wqkv + (size_t)sel * 1048576) : wo;
  }
  const float4* p = (const float4*)src + (size_t)j * 2;
  float4 a = p[0], b = p[1];
  u16x8 o;
  o[0] = f2bf(a.x); o[1] = f2bf(a.y); o[2] = f2bf(a.z); o[3] = f2bf(a.w);
  o[4] = f2bf(b.x); o[5] = f2bf(b.y); o[6] = f2bf(b.z); o[7] = f2bf(b.w);
  ((u16x8*)dst)[j] = o;
}

// ---------------- bf16 GEMM, B^T layout (out[m,n] = sum_k A[m,k]*W[n,k]) ----
// 128x128 tile, BK=64, multi-block/CU implicit overlap. No XCD swizzle
// (r4/r5 A/B: swizzle FETCH 143->210MB, +3.5% time). A bf16 via gload_lds
// (r6 A/B: fp32 reg-staged fused cast = 104->180us regression).
template<int MODE>
__global__ __launch_bounds__(256, 2) void gemm_bt(
    const unsigned short* __restrict__ A, const unsigned short* __restrict__ Bw,
    void* __restrict__ out0, unsigned short* __restrict__ qp,
    unsigned short* __restrict__ kp, unsigned short* __restrict__ vp,
    int K, int N, int nTn)
{
  __shared__ unsigned short sA[128 * 64];
  __shared__ unsigned short sB[128 * 64];
  int t = threadIdx.x, w = t >> 6, lane = t & 63, fr = lane & 15, fq = lane >> 4;
  int bid = blockIdx.x;
  int bm = bid / nTn, bn = bid % nTn;
  int wm = w >> 1, wn = w & 1;

  f32x4 acc[4][4];
  f32x4 z4 = {0.f, 0.f, 0.f, 0.f};
#pragma unroll
  for (int mi = 0; mi < 4; ++mi)
#pragma unroll
    for (int ni = 0; ni < 4; ++ni) acc[mi][ni] = z4;

  for (int k0 = 0; k0 < K; k0 += 64) {
#pragma unroll
    for (int i = 0; i < 4; ++i) {
      int p = (i * 4 + w) * 64 + lane;
      int r = p >> 3;
      int c8 = (p & 7) ^ (r & 7);  // inverse-swizzled source column-chunk
      gload16(A + (size_t)(bm * 128 + r) * K + k0 + c8 * 8, &sA[(i * 4 + w) * 512]);
      gload16(Bw + (size_t)(bn * 128 + r) * K + k0 + c8 * 8, &sB[(i * 4 + w) * 512]);
    }
    __syncthreads();
#pragma unroll
    for (int ks = 0; ks < 2; ++ks) {
      bf16x8 af[4], bg[4];
#pragma unroll
      for (int mi = 0; mi < 4; ++mi) {
        int r = wm * 64 + mi * 16 + fr;
        int c8 = (ks * 4 + fq) ^ (r & 7);
        af[mi] = *(const bf16x8*)&sA[(r * 8 + c8) * 8];
      }
#pragma unroll
      for (int ni = 0; ni < 4; ++ni) {
        int r = wn * 64 + ni * 16 + fr;
        int c8 = (ks * 4 + fq) ^ (r & 7);
        bg[ni] = *(const bf16x8*)&sB[(r * 8 + c8) * 8];
      }
#pragma unroll
      for (int mi = 0; mi < 4; ++mi)
#pragma unroll
        for (int ni = 0; ni < 4; ++ni)
          acc[mi][ni] = __builtin_amdgcn_mfma_f32_16x16x32_bf16(af[mi], bg[ni], acc[mi][ni], 0, 0, 0);
    }
    __syncthreads();
  }

  if (MODE == 0) {
    float* O = (float*)out0;
#pragma unroll
    for (int mi = 0; mi < 4; ++mi)
#pragma unroll
      for (int ni = 0; ni < 4; ++ni)
#pragma unroll
        for (int j = 0; j < 4; ++j) {
          int m = bm * 128 + wm * 64 + mi * 16 + fq * 4 + j;
          int n = bn * 128 + wn * 64 + ni * 16 + fr;
          O[(size_t)m * N + n] = acc[mi][ni][j];
        }
  } else {
    int tsel = (bn * 128) >> 10;  // 0:Q 1:K 2:V (whole block in one tensor)
    unsigned short* base = (tsel == 0) ? qp : ((tsel == 1) ? kp : vp);
#pragma unroll
    for (int mi = 0; mi < 4; ++mi)
#pragma unroll
      for (int ni = 0; ni < 4; ++ni)
#pragma unroll
        for (int j = 0; j < 4; ++j) {
          int m = bm * 128 + wm * 64 + mi * 16 + fq * 4 + j;  // b*4096 + l
          int n = bn * 128 + wn * 64 + ni * 16 + fr;
          int col1 = n & 1023;
          int h = col1 >> 6, d = col1 & 63;
          int b = m >> 12, l = m & 4095;
          float v = acc[mi][ni][j];
          if (tsel < 2) v = (v > 0.f) ? (v + 1.f) : __expf(v);  // elu(v)+1
          base[(((size_t)(b * 16 + h)) * 4096 + l) * 64 + d] = f2bf(v);
        }
  }
}

// ---------------- pass 1: per-chunk state via MFMA ---------------------------
// S_c[e][d] = sum_s v[s][e]*k[s][d]  (stored Sbuf[bh][c][e][d]); z_c[d] = sum_s k[s][d]
// Staging: lane=d coalesced u16 global loads -> b128 LDS writes into [d][136].
__global__ __launch_bounds__(256) void chunk_state(
    const unsigned short* __restrict__ kb, const unsigned short* __restrict__ vb,
    float* __restrict__ Sbuf, float* __restrict__ zbuf)
{
  __shared__ unsigned short kT[64 * 136];
  __shared__ unsigned short vT[64 * 136];
  int t = threadIdx.x, w = t >> 6, lane = t & 63, fr = lane & 15, fq = lane >> 4;
  int bh = blockIdx.x >> 5, c = blockIdx.x & 31;
  size_t base = ((size_t)bh * 4096 + (size_t)c * 128) * 64;

  int d = lane;          // wave-contiguous -> 128B coalesced per load instr
  int s0 = w * 8;
#pragma unroll
  for (int c4 = 0; c4 < 4; ++c4) {
    int sb = c4 * 32 + s0;
    u16x8 kr, vr;
#pragma unroll
    for (int i = 0; i < 8; ++i) {
      kr[i] = kb[base + (size_t)(sb + i) * 64 + d];
      vr[i] = vb[base + (size_t)(sb + i) * 64 + d];
    }
    *(u16x8*)&kT[d * 136 + sb] = kr;
    *(u16x8*)&vT[d * 136 + sb] = vr;
  }
  __syncthreads();

  f32x4 acc[4];
  f32x4 z4 = {0.f, 0.f, 0.f, 0.f};
#pragma unroll
  for (int n = 0; n < 4; ++n) acc[n] = z4;
#pragma unroll
  for (int ks = 0; ks < 4; ++ks) {
    bf16x8 av = *(const bf16x8*)&vT[(w * 16 + fr) * 136 + ks * 32 + fq * 8];
#pragma unroll
    for (int n = 0; n < 4; ++n) {
      bf16x8 bk = *(const bf16x8*)&kT[(n * 16 + fr) * 136 + ks * 32 + fq * 8];
      acc[n] = __builtin_amdgcn_mfma_f32_16x16x32_bf16(av, bk, acc[n], 0, 0, 0);
    }
  }
  size_t ob = ((size_t)bh * 32 + c) * 4096;
#pragma unroll
  for (int n = 0; n < 4; ++n)
#pragma unroll
    for (int j = 0; j < 4; ++j) {
      int e = w * 16 + fq * 4 + j, dd = n * 16 + fr;
      Sbuf[ob + (size_t)e * 64 + dd] = acc[n][j];
    }
  if (t < 64) {
    float z = 0.f;
#pragma unroll
    for (int i = 0; i < 16; ++i) {
      u16x8 kr = *(const u16x8*)&kT[t * 136 + i * 8];
#pragma unroll
      for (int j = 0; j < 8; ++j) z += b2f(kr[j]);
    }
    zbuf[((size_t)bh * 32 + c) * 64 + t] = z;
  }
}

// ---------------- pass 2: parallel exclusive prefix (S blocks then z blocks) -
__global__ __launch_bounds__(256) void scan_all(
    const float* __restrict__ Sbuf, const float* __restrict__ zbuf,
    unsigned short* __restrict__ Spref, float* __restrict__ zpref)
{
  if (blockIdx.x < 1024) {
    int idx = blockIdx.x * 256 + threadIdx.x;  // 262144 sequences
    int bh = idx >> 12, i = idx & 4095;
    size_t base = (size_t)bh * 32 * 4096 + i;
    float run = 0.f;
#pragma unroll
    for (int c = 0; c < 32; ++c) {
      float v = Sbuf[base + (size_t)c * 4096];
      Spref[base + (size_t)c * 4096] = f2bf(run);
      run += v;
    }
  } else {
    int idx = (blockIdx.x - 1024) * 256 + threadIdx.x;  // 4096 sequences
    size_t base = (size_t)(idx >> 6) * 32 * 64 + (idx & 63);
    float run = 0.f;
#pragma unroll
    for (int c = 0; c < 32; ++c) {
      float v = zbuf[base + c * 64];
      zpref[base + c * 64] = run;
      run += v;
    }
  }
}

// ---------------- pass 3: per-chunk output ----------------------------------
// v2: swapped QK^T (C[s][m]) -> in-register causal mask, 2-shfl rowsum,
// P->LDS as b32 pair writes (32 vs 64 scalar). PV/QS side unchanged.
__global__ __launch_bounds__(256, 2) void chunk_out(
    const unsigned short* __restrict__ qb, const unsigned short* __restrict__ kb,
    const unsigned short* __restrict__ vb, const unsigned short* __restrict__ Spref,
    const float* __restrict__ zpref, unsigned short* __restrict__ attn)
{
  __shared__ unsigned short sq[128 * 64];   // q, swizzled (&7)
  __shared__ unsigned short skv[128 * 64];  // k (swz &7), then v^T [64][128] (swz &15)
  __shared__ unsigned short ss[128 * 128];  // P bf16 [m][s] (swz &15)
  __shared__ unsigned short sS[80 * 64];    // state rows e=0..63, z at 64, zeros 65..79
  int t = threadIdx.x, w = t >> 6, lane = t & 63, fr = lane & 15, fq = lane >> 4;
  int bh = blockIdx.x >> 5, c = blockIdx.x & 31;
  size_t qkbase = ((size_t)bh * 4096 + (size_t)c * 128) * 64;
  size_t sbase = ((size_t)bh * 32 + c) * 4096;

  u16x8 vreg[4];  // v chunk staged to regs early (T14-style)
#pragma unroll
  for (int i = 0; i < 4; ++i)
    vreg[i] = *(const u16x8*)(vb + qkbase + (size_t)(t * 4 + i) * 8);

#pragma unroll
  for (int i = 0; i < 4; ++i) {
    int p = t * 4 + i, r = p >> 3, c8 = p & 7;
    int sw = (r * 8 + (c8 ^ (r & 7))) * 8;
    *(u16x8*)&sq[sw] = *(const u16x8*)(qb + qkbase + (size_t)p * 8);
    *(u16x8*)&skv[sw] = *(const u16x8*)(kb + qkbase + (size_t)p * 8);
  }
#pragma unroll
  for (int i = 0; i < 2; ++i) {
    int p = t * 2 + i, e = p >> 3, c8 = p & 7;
    *(u16x8*)&sS[(e * 8 + (c8 ^ (e & 7))) * 8] = *(const u16x8*)(Spref + sbase + (size_t)p * 8);
  }
  if (t < 64) sS[64 * 64 + t] = f2bf(zpref[((size_t)bh * 32 + c) * 64 + t]);
  {
    unsigned int* zz = (unsigned int*)&sS[65 * 64];
    for (int i = t; i < 480; i += 256) zz[i] = 0u;
  }
  __syncthreads();

  int rowbase = w * 32;
  bf16x8 aq[2][2];
#pragma unroll
  for (int mi = 0; mi < 2; ++mi)
#pragma unroll
    for (int kt = 0; kt < 2; ++kt) {
      int r = rowbase + mi * 16 + fr;
      int c8 = (kt * 4 + fq) ^ (r & 7);
      aq[mi][kt] = *(const bf16x8*)&sq[(r * 8 + c8) * 8];
    }

  // swapped QK^T: accsT[mi][ni] = C[s-tile ni][m-tile mi]; lane holds
  // P[s = ni*16+fq*4+j][m = rowbase+mi*16+fr]
  f32x4 accsT[2][8];
  f32x4 z4 = {0.f, 0.f, 0.f, 0.f};
#pragma unroll
  for (int mi = 0; mi < 2; ++mi)
#pragma unroll
    for (int ni = 0; ni < 8; ++ni) accsT[mi][ni] = z4;

#pragma unroll
  for (int ni = 0; ni < 8; ++ni)
#pragma unroll
    for (int kt = 0; kt < 2; ++kt) {
      int r = ni * 16 + fr;
      int c8 = (kt * 4 + fq) ^ (r & 7);
      bf16x8 bk = *(const bf16x8*)&skv[(r * 8 + c8) * 8];
      accsT[0][ni] = __builtin_amdgcn_mfma_f32_16x16x32_bf16(bk, aq[0][kt], accsT[0][ni], 0, 0, 0);
      accsT[1][ni] = __builtin_amdgcn_mfma_f32_16x16x32_bf16(bk, aq[1][kt], accsT[1][ni], 0, 0, 0);
    }

  // in-register causal mask + rowsum (per lane: m = rowbase+mi*16+fr)
  float rs[2];
#pragma unroll
  for (int mi = 0; mi < 2; ++mi) {
    int m16 = mi * 16 + fr;        // m - rowbase
    float sum = 0.f;
#pragma unroll
    for (int ni = 0; ni < 8; ++ni)
#pragma unroll
      for (int j = 0; j < 4; ++j) {
        int s = ni * 16 + fq * 4 + j - rowbase;  // s - rowbase
        float v = (s <= m16) ? accsT[mi][ni][j] : 0.f;
        accsT[mi][ni][j] = v;
        sum += v;
      }
    sum += __shfl_xor(sum, 16, 64);
    sum += __shfl_xor(sum, 32, 64);
    rs[mi] = sum;
  }
  __syncthreads();  // all waves done reading k from skv

  // write v^T into skv (row e, col s; swizzle &15)
#pragma unroll
  for (int i = 0; i < 4; ++i) {
    int p = t * 4 + i, s = p >> 3, e0g = (p & 7) * 8;
#pragma unroll
    for (int j = 0; j < 8; ++j) {
      int e = e0g + j;
      skv[(e * 16 + ((s >> 3) ^ (e & 15))) * 8 + (s & 7)] = vreg[i][j];
    }
  }
  // P -> ss as packed b32 pairs: addr chunk (2ni+(fq>>1))^(m&15), off (fq&1)*4+2p
#pragma unroll
  for (int mi = 0; mi < 2; ++mi) {
    int m = rowbase + mi * 16 + fr;
#pragma unroll
    for (int ni = 0; ni < 8; ++ni)
#pragma unroll
      for (int p = 0; p < 2; ++p) {
        unsigned int pk = (unsigned int)f2bf(accsT[mi][ni][2 * p]) |
                          ((unsigned int)f2bf(accsT[mi][ni][2 * p + 1]) << 16);
        int chunk = (2 * ni + (fq >> 1)) ^ (m & 15);
        *(unsigned int*)&ss[m * 128 + chunk * 8 + (fq & 1) * 4 + 2 * p] = pk;
      }
  }
  __syncthreads();

  f32x4 acco[2][4];
  f32x4 accd[2];
#pragma unroll
  for (int mi = 0; mi < 2; ++mi) {
    accd[mi] = z4;
#pragma unroll
    for (int ni = 0; ni < 4; ++ni) acco[mi][ni] = z4;
  }
  // inter-chunk: q @ S (+ den column from z row)
#pragma unroll
  for (int kt = 0; kt < 2; ++kt) {
#pragma unroll
    for (int ni = 0; ni < 4; ++ni) {
      int r = ni * 16 + fr;
      int c8 = (kt * 4 + fq) ^ (r & 7);
      bf16x8 bS = *(const bf16x8*)&sS[(r * 8 + c8) * 8];
      acco[0][ni] = __builtin_amdgcn_mfma_f32_16x16x32_bf16(aq[0][kt], bS, acco[0][ni], 0, 0, 0);
      acco[1][ni] = __builtin_amdgcn_mfma_f32_16x16x32_bf16(aq[1][kt], bS, acco[1][ni], 0, 0, 0);
    }
    {
      int r = 64 + fr;
      int c8 = (kt * 4 + fq) ^ (r & 7);
      bf16x8 bz = *(const bf16x8*)&sS[(r * 8 + c8) * 8];
      accd[0] = __builtin_amdgcn_mfma_f32_16x16x32_bf16(aq[0][kt], bz, accd[0], 0, 0, 0);
      accd[1] = __builtin_amdgcn_mfma_f32_16x16x32_bf16(aq[1][kt], bz, accd[1], 0, 0, 0);
    }
  }
  // intra-chunk: masked P @ v
#pragma unroll
  for (int kt = 0; kt < 4; ++kt) {
    bf16x8 am[2];
#pragma unroll
    for (int mi = 0; mi < 2; ++mi) {
      int r = rowbase + mi * 16 + fr;
      int c8 = (kt * 4 + fq) ^ (r & 15);
      am[mi] = *(const bf16x8*)&ss[(r * 16 + c8) * 8];
    }
#pragma unroll
    for (int ni = 0; ni < 4; ++ni) {
      int r = ni * 16 + fr;
      int c8 = (kt * 4 + fq) ^ (r & 15);
      bf16x8 bv = *(const bf16x8*)&skv[(r * 16 + c8) * 8];
      acco[0][ni] = __builtin_amdgcn_mfma_f32_16x16x32_bf16(am[0], bv, acco[0][ni], 0, 0, 0);
      acco[1][ni] = __builtin_amdgcn_mfma_f32_16x16x32_bf16(am[1], bv, acco[1][ni], 0, 0, 0);
    }
  }

  int b = bh >> 4, h = bh & 15;
#pragma unroll
  for (int mi = 0; mi < 2; ++mi)
#pragma unroll
    for (int j = 0; j < 4; ++j) {
      float rsj = __shfl(rs[mi], fq * 4 + j, 64);  // rowsum for m16 = fq*4+j
      float den = __shfl(accd[mi][j], (lane & 48), 64) + rsj;
      float rden = 1.f / den;
      int m = rowbase + mi * 16 + fq * 4 + j;
      size_t rowoff = ((size_t)b * 4096 + (size_t)c * 128 + m) * 1024 + h * 64;
#pragma unroll
      for (int ni = 0; ni < 4; ++ni) {
        int e = ni * 16 + fr;
        float o = acco[mi][ni][j] * rden + 1e-12f;
        attn[rowoff + e] = f2bf(o);
      }
    }
}

// ---------------- host launch ------------------------------------------------
extern "C" void kernel_launch(void* const* d_in, const int* in_sizes, int n_in,
                              void* d_out, int out_size, void* d_ws, size_t ws_size,
                              hipStream_t stream) {
  (void)in_sizes; (void)n_in; (void)out_size; (void)ws_size;
  const float* x = (const float*)d_in[0];
  const float* Wq = (const float*)d_in[1];
  const float* Wk = (const float*)d_in[2];
  const float* Wv = (const float*)d_in[3];
  const float* Wo = (const float*)d_in[4];
  char* ws = (char*)d_ws;
  unsigned short* xbf  = (unsigned short*)(ws + 0);          // 33554432 B
  unsigned short* wqkv = (unsigned short*)(ws + 33554432);   // 6291456 B
  unsigned short* wo   = (unsigned short*)(ws + 39845888);   // 2097152 B
  unsigned short* q    = (unsigned short*)(ws + 41943040);   // 33554432 B
  unsigned short* k    = (unsigned short*)(ws + 75497472);   // 33554432 B
  unsigned short* v    = (unsigned short*)(ws + 109051904);  // 33554432 B
  unsigned short* attn = (unsigned short*)(ws + 142606336);  // 33554432 B
  float* Sbuf          = (float*)(ws + 176160768);           // 33554432 B
  unsigned short* Spref= (unsigned short*)(ws + 209715200);  // 16777216 B
  float* zbuf          = (float*)(ws + 226492416);           // 524288 B
  float* zpref         = (float*)(ws + 227016704);           // 524288 B

  cast_all<<<10240, 256, 0, stream>>>(x, Wq, Wk, Wv, Wo, xbf, wqkv, wo);
  gemm_bt<1><<<3072, 256, 0, stream>>>(xbf, wqkv, nullptr, q, k, v, 1024, 3072, 24);
  chunk_state<<<2048, 256, 0, stream>>>(k, v, Sbuf, zbuf);
  scan_all<<<1040, 256, 0, stream>>>(Sbuf, zbuf, Spref, zpref);
  chunk_out<<<2048, 256, 0, stream>>>(q, k, v, Spref, zpref, attn);
  gemm_bt<0><<<1024, 256, 0, stream>>>(attn, wo, d_out, nullptr, nullptr, nullptr, 1024, 1024, 8);
}